// Round 3
// baseline (441.705 us; speedup 1.0000x reference)
//
#include <hip/hip_runtime.h>
#include <math.h>

// ============================================================================
// MEASUREMENT ROUND: identical kernels to round 2, but bias_kernel is launched
// 4x (idempotent). dur_us delta vs round 2 = 3 * bias_time. This pins down
// whether the bias stream is at its ~45 us write floor or ~2x above it.
// ============================================================================

#define T_TOK 2048
#define H_DIM 2048
#define V_DIM 32000
#define NE    16

typedef float fvec4 __attribute__((ext_vector_type(4)));

// ws layout:
//   scores: NE * T_TOK floats (transposed: scores[e*T_TOK + t])  = 128 KB
//   params: T_TOK float4s, offset 128 KB                          = 32 KB
#define WS_SCORES(ws)  ((float*)(ws))
#define WS_PARAMS(ws)  ((float4*)((char*)(ws) + NE * T_TOK * sizeof(float)))

// ---------------------------------------------------------------------------
// Kernel 1: gating. One block (256 thr) per token. (unchanged)
// ---------------------------------------------------------------------------
__global__ __launch_bounds__(256) void gate_kernel(const float4* __restrict__ hs,
                                                   const float4* __restrict__ gw,
                                                   float* __restrict__ scores,
                                                   float4* __restrict__ params)
{
    const int t   = blockIdx.x;
    const int tid = threadIdx.x;
    const int H4  = H_DIM / 4;   // 512

    float acc[NE];
#pragma unroll
    for (int e = 0; e < NE; ++e) acc[e] = 0.f;

    const float4* hrow = hs + (size_t)t * H4;
#pragma unroll
    for (int i = tid; i < H4; i += 256) {     // 2 iterations
        float4 x = hrow[i];
#pragma unroll
        for (int e = 0; e < NE; ++e) {
            float4 g = gw[e * H4 + i];
            acc[e] += x.x * g.x + x.y * g.y + x.z * g.z + x.w * g.w;
        }
    }

    // 64-lane shuffle reduction per accumulator
#pragma unroll
    for (int e = 0; e < NE; ++e) {
        float v = acc[e];
#pragma unroll
        for (int off = 32; off > 0; off >>= 1) v += __shfl_down(v, off, 64);
        acc[e] = v;
    }

    __shared__ float partial[4][NE];
    __shared__ float exps[NE + 1];   // [NE] = softmax denominator

    const int wave = tid >> 6, lane = tid & 63;
    if (lane == 0) {
#pragma unroll
        for (int e = 0; e < NE; ++e) partial[wave][e] = acc[e];
    }
    __syncthreads();

    if (tid == 0) {
        float logits[NE];
        float m = -INFINITY;
#pragma unroll
        for (int e = 0; e < NE; ++e) {
            logits[e] = partial[0][e] + partial[1][e] + partial[2][e] + partial[3][e];
            m = fmaxf(m, logits[e]);
        }
        float Z = 0.f;
#pragma unroll
        for (int e = 0; e < NE; ++e) { float ex = expf(logits[e] - m); exps[e] = ex; Z += ex; }
        exps[NE] = Z;

        // top-2, strict > ascending scan => lowest index wins ties (jax semantics)
        int i0 = 0; float l0 = logits[0];
#pragma unroll
        for (int e = 1; e < NE; ++e) if (logits[e] > l0) { l0 = logits[e]; i0 = e; }
        int i1 = -1; float l1 = -INFINITY;
#pragma unroll
        for (int e = 0; e < NE; ++e) if (e != i0 && logits[e] > l1) { l1 = logits[e]; i1 = e; }

        float e0 = exps[i0], e1 = exps[i1];
        float inv = 1.f / (e0 + e1);
        params[t] = make_float4(e0 * inv, e1 * inv, __int_as_float(i0), __int_as_float(i1));
    }
    __syncthreads();

    if (tid < NE)
        scores[tid * T_TOK + t] = exps[tid] / exps[NE];
}

// ---------------------------------------------------------------------------
// Kernel 2: bias = w0*eb[i0,:] + w1*eb[i1,:]. (unchanged from round 2)
// ---------------------------------------------------------------------------
#define CHUNKS_PER_TOK 8
#define CHUNK_V4 (V_DIM / 4 / CHUNKS_PER_TOK)   // 1000

__global__ __launch_bounds__(256) void bias_kernel(const float4* __restrict__ eb,
                                                   const float4* __restrict__ params,
                                                   float4* __restrict__ out)
{
    const int V4    = V_DIM / 4;                 // 8000
    const int t     = blockIdx.x >> 3;           // token
    const int chunk = blockIdx.x & 7;
    const int tid   = threadIdx.x;

    float4 p = params[t];                        // uniform address per block
    const int   i0 = __builtin_amdgcn_readfirstlane(__float_as_int(p.z));
    const int   i1 = __builtin_amdgcn_readfirstlane(__float_as_int(p.w));
    const float w0 = __int_as_float(__builtin_amdgcn_readfirstlane(__float_as_int(p.x)));
    const float w1 = __int_as_float(__builtin_amdgcn_readfirstlane(__float_as_int(p.y)));

    const int v0 = chunk * CHUNK_V4;
    const float4* r0 = eb + (size_t)i0 * V4 + v0;     // SGPR base
    const float4* r1 = eb + (size_t)i1 * V4 + v0;     // SGPR base
    fvec4* o = (fvec4*)(out + (size_t)t * V4 + v0);

    // 1000 = 3*256 + 232: 3 full sweeps, tid<232 does one extra.
#pragma unroll 4
    for (int v = tid; v < CHUNK_V4; v += 256) {
        float4 a = r0[v];
        float4 b = r1[v];
        fvec4 r;
        r.x = w0 * a.x + w1 * b.x;
        r.y = w0 * a.y + w1 * b.y;
        r.z = w0 * a.z + w1 * b.z;
        r.w = w0 * a.w + w1 * b.w;
        __builtin_nontemporal_store(r, o + v);
    }
}

// ---------------------------------------------------------------------------
// Kernel 3: usage + aux loss. (unchanged)
// ---------------------------------------------------------------------------
__global__ __launch_bounds__(1024) void aux_kernel(const float* __restrict__ scores,
                                                   float* __restrict__ out)
{
    const int e    = threadIdx.x >> 6;   // wave id = expert
    const int lane = threadIdx.x & 63;

    float s = 0.f;
    const float* row = scores + e * T_TOK;
#pragma unroll
    for (int i = lane; i < T_TOK; i += 64) s += row[i];   // 32 iterations
#pragma unroll
    for (int off = 32; off > 0; off >>= 1) s += __shfl_down(s, off, 64);

    __shared__ float u[NE];
    if (lane == 0) u[e] = s;
    __syncthreads();

    if (threadIdx.x == 0) {
        float aux = 0.f;
#pragma unroll
        for (int i = 0; i < NE; ++i) {
            float ui = u[i] / (float)T_TOK;
            aux += ui * logf(ui);
        }
        out[0] = aux * (float)NE;
    }
}

extern "C" void kernel_launch(void* const* d_in, const int* in_sizes, int n_in,
                              void* d_out, int out_size, void* d_ws, size_t ws_size,
                              hipStream_t stream)
{
    const float* hs = (const float*)d_in[0];   // (T, H)
    const float* gw = (const float*)d_in[1];   // (E, H)
    const float* eb = (const float*)d_in[2];   // (E, V)
    float* out = (float*)d_out;                // T*V floats then 1 aux float

    float*  scores = WS_SCORES(d_ws);
    float4* params = WS_PARAMS(d_ws);

    gate_kernel<<<T_TOK, 256, 0, stream>>>((const float4*)hs, (const float4*)gw,
                                           scores, params);

    // MEASUREMENT: 4 identical (idempotent) bias launches.
    // dur_us - 304.4 = 3 * bias_time.
    for (int rep = 0; rep < 4; ++rep) {
        bias_kernel<<<T_TOK * CHUNKS_PER_TOK, 256, 0, stream>>>((const float4*)eb, params,
                                                                (float4*)out);
    }

    aux_kernel<<<1, 1024, 0, stream>>>(scores, out + (size_t)T_TOK * V_DIM);
}

// Round 4
// 300.906 us; speedup vs baseline: 1.4679x; 1.4679x over previous
//
#include <hip/hip_runtime.h>
#include <math.h>

#define T_TOK 2048
#define H_DIM 2048
#define V_DIM 32000
#define NE    16

typedef float fvec4 __attribute__((ext_vector_type(4)));

// ws layout:
//   scores: NE * T_TOK floats (transposed: scores[e*T_TOK + t])  = 128 KB
//   params: T_TOK float4s, offset 128 KB                          = 32 KB
#define WS_SCORES(ws)  ((float*)(ws))
#define WS_PARAMS(ws)  ((float4*)((char*)(ws) + NE * T_TOK * sizeof(float)))

// ---------------------------------------------------------------------------
// Kernel 1: gating, lean re-structure. One block (256 thr = 4 waves) per
// token. Wave w owns experts [4w, 4w+4) across the FULL hidden dim:
//   - acc[4] per thread instead of acc[16]  -> ~half the VGPRs
//   - 5 load streams/iter instead of 17     -> short dependence tail
//   - 24 shuffle ops instead of 96
//   - each wave's shuffle reduction is final (covers all of H); no
//     cross-wave partial combine needed.
// Serial thread-0 softmax + top-2 tail kept verbatim (verified semantics:
// strict > ascending scan => lowest index wins ties, like jax top_k).
// ---------------------------------------------------------------------------
__global__ __launch_bounds__(256) void gate_kernel(const float4* __restrict__ hs,
                                                   const float4* __restrict__ gw,
                                                   float* __restrict__ scores,
                                                   float4* __restrict__ params)
{
    const int t    = blockIdx.x;
    const int tid  = threadIdx.x;
    const int wave = tid >> 6;        // 0..3 -> experts 4w..4w+3
    const int lane = tid & 63;
    const int H4   = H_DIM / 4;       // 512

    const float4* hrow = hs + (size_t)t * H4;
    const float4* g0 = gw + (size_t)(4 * wave + 0) * H4;
    const float4* g1 = gw + (size_t)(4 * wave + 1) * H4;
    const float4* g2 = gw + (size_t)(4 * wave + 2) * H4;
    const float4* g3 = gw + (size_t)(4 * wave + 3) * H4;

    float a0 = 0.f, a1 = 0.f, a2 = 0.f, a3 = 0.f;
    // 512 float4 / 64 lanes = 8 iterations; unroll 4 keeps ~20 loads in
    // flight without blowing the register file.
#pragma unroll 4
    for (int j = 0; j < 8; ++j) {
        const int idx = j * 64 + lane;           // coalesced across lanes
        float4 x  = hrow[idx];
        float4 p0 = g0[idx];
        float4 p1 = g1[idx];
        float4 p2 = g2[idx];
        float4 p3 = g3[idx];
        a0 += x.x * p0.x + x.y * p0.y + x.z * p0.z + x.w * p0.w;
        a1 += x.x * p1.x + x.y * p1.y + x.z * p1.z + x.w * p1.w;
        a2 += x.x * p2.x + x.y * p2.y + x.z * p2.z + x.w * p2.w;
        a3 += x.x * p3.x + x.y * p3.y + x.z * p3.z + x.w * p3.w;
    }

    // 64-lane shuffle reduction; result on lane 0 is the FINAL logit.
#pragma unroll
    for (int off = 32; off > 0; off >>= 1) {
        a0 += __shfl_down(a0, off, 64);
        a1 += __shfl_down(a1, off, 64);
        a2 += __shfl_down(a2, off, 64);
        a3 += __shfl_down(a3, off, 64);
    }

    __shared__ float logits_s[NE];
    __shared__ float exps[NE + 1];   // [NE] = softmax denominator

    if (lane == 0) {
        logits_s[4 * wave + 0] = a0;
        logits_s[4 * wave + 1] = a1;
        logits_s[4 * wave + 2] = a2;
        logits_s[4 * wave + 3] = a3;
    }
    __syncthreads();

    if (tid == 0) {
        float logits[NE];
        float m = -INFINITY;
#pragma unroll
        for (int e = 0; e < NE; ++e) {
            logits[e] = logits_s[e];
            m = fmaxf(m, logits[e]);
        }
        float Z = 0.f;
#pragma unroll
        for (int e = 0; e < NE; ++e) { float ex = expf(logits[e] - m); exps[e] = ex; Z += ex; }
        exps[NE] = Z;

        // top-2, strict > ascending scan => lowest index wins ties (jax semantics)
        int i0 = 0; float l0 = logits[0];
#pragma unroll
        for (int e = 1; e < NE; ++e) if (logits[e] > l0) { l0 = logits[e]; i0 = e; }
        int i1 = -1; float l1 = -INFINITY;
#pragma unroll
        for (int e = 0; e < NE; ++e) if (e != i0 && logits[e] > l1) { l1 = logits[e]; i1 = e; }

        float e0 = exps[i0], e1 = exps[i1];
        float inv = 1.f / (e0 + e1);
        params[t] = make_float4(e0 * inv, e1 * inv, __int_as_float(i0), __int_as_float(i1));
    }
    __syncthreads();

    if (tid < NE)
        scores[tid * T_TOK + t] = exps[tid] / exps[NE];
}

// ---------------------------------------------------------------------------
// Kernel 2: bias = w0*eb[i0,:] + w1*eb[i1,:]. UNCHANGED from round 2 —
// measured at 45.8 us = ~91% of achievable HBM write BW (262 MB stream).
// ---------------------------------------------------------------------------
#define CHUNKS_PER_TOK 8
#define CHUNK_V4 (V_DIM / 4 / CHUNKS_PER_TOK)   // 1000

__global__ __launch_bounds__(256) void bias_kernel(const float4* __restrict__ eb,
                                                   const float4* __restrict__ params,
                                                   float4* __restrict__ out)
{
    const int V4    = V_DIM / 4;                 // 8000
    const int t     = blockIdx.x >> 3;           // token
    const int chunk = blockIdx.x & 7;
    const int tid   = threadIdx.x;

    float4 p = params[t];                        // uniform address per block
    const int   i0 = __builtin_amdgcn_readfirstlane(__float_as_int(p.z));
    const int   i1 = __builtin_amdgcn_readfirstlane(__float_as_int(p.w));
    const float w0 = __int_as_float(__builtin_amdgcn_readfirstlane(__float_as_int(p.x)));
    const float w1 = __int_as_float(__builtin_amdgcn_readfirstlane(__float_as_int(p.y)));

    const int v0 = chunk * CHUNK_V4;
    const float4* r0 = eb + (size_t)i0 * V4 + v0;     // SGPR base
    const float4* r1 = eb + (size_t)i1 * V4 + v0;     // SGPR base
    fvec4* o = (fvec4*)(out + (size_t)t * V4 + v0);

    // 1000 = 3*256 + 232: 3 full sweeps, tid<232 does one extra.
#pragma unroll 4
    for (int v = tid; v < CHUNK_V4; v += 256) {
        float4 a = r0[v];
        float4 b = r1[v];
        fvec4 r;
        r.x = w0 * a.x + w1 * b.x;
        r.y = w0 * a.y + w1 * b.y;
        r.z = w0 * a.z + w1 * b.z;
        r.w = w0 * a.w + w1 * b.w;
        __builtin_nontemporal_store(r, o + v);
    }
}

// ---------------------------------------------------------------------------
// Kernel 3: usage + aux loss. UNCHANGED.
// ---------------------------------------------------------------------------
__global__ __launch_bounds__(1024) void aux_kernel(const float* __restrict__ scores,
                                                   float* __restrict__ out)
{
    const int e    = threadIdx.x >> 6;   // wave id = expert
    const int lane = threadIdx.x & 63;

    float s = 0.f;
    const float* row = scores + e * T_TOK;
#pragma unroll
    for (int i = lane; i < T_TOK; i += 64) s += row[i];   // 32 iterations
#pragma unroll
    for (int off = 32; off > 0; off >>= 1) s += __shfl_down(s, off, 64);

    __shared__ float u[NE];
    if (lane == 0) u[e] = s;
    __syncthreads();

    if (threadIdx.x == 0) {
        float aux = 0.f;
#pragma unroll
        for (int i = 0; i < NE; ++i) {
            float ui = u[i] / (float)T_TOK;
            aux += ui * logf(ui);
        }
        out[0] = aux * (float)NE;
    }
}

extern "C" void kernel_launch(void* const* d_in, const int* in_sizes, int n_in,
                              void* d_out, int out_size, void* d_ws, size_t ws_size,
                              hipStream_t stream)
{
    const float* hs = (const float*)d_in[0];   // (T, H)
    const float* gw = (const float*)d_in[1];   // (E, H)
    const float* eb = (const float*)d_in[2];   // (E, V)
    float* out = (float*)d_out;                // T*V floats then 1 aux float

    float*  scores = WS_SCORES(d_ws);
    float4* params = WS_PARAMS(d_ws);

    gate_kernel<<<T_TOK, 256, 0, stream>>>((const float4*)hs, (const float4*)gw,
                                           scores, params);

    bias_kernel<<<T_TOK * CHUNKS_PER_TOK, 256, 0, stream>>>((const float4*)eb, params,
                                                            (float4*)out);

    aux_kernel<<<1, 1024, 0, stream>>>(scores, out + (size_t)T_TOK * V_DIM);
}